// Round 2
// baseline (424.609 us; speedup 1.0000x reference)
//
#include <hip/hip_runtime.h>
#include <cmath>

#define DEV __device__ __forceinline__

constexpr int B_SZ = 16;
constexpr int LSEQ = 256;
constexpr int DM   = 256;   // d_model
constexpr int DI   = 512;   // d_inner
constexpr int TLEN = 16;

DEV float silu_f(float x)     { return x / (1.f + __expf(-x)); }
DEV float softplus_f(float x) { return log1pf(__expf(x)); }

// ---------------------------------------------------------------------------
// K1: in-projection (x part only): xi_pre[(b*L+l)*DI + j] = sum_k x[b,k,l]*W_in[j,k]
// ---------------------------------------------------------------------------
__global__ __launch_bounds__(256) void k_inproj(const float* __restrict__ x,
                                                const float* __restrict__ W_in,
                                                float* __restrict__ xi_pre) {
    __shared__ float As[32][68];
    __shared__ float Ws[32][68];
    const int by = blockIdx.y, bx = blockIdx.x;
    const int row0 = by * 64;
    const int b = row0 >> 8, l0 = row0 & 255;
    const int j0 = bx * 64;
    const int tid = threadIdx.x;
    const int ty = tid >> 4, tx = tid & 15;
    const float* xb = x + (size_t)b * DM * LSEQ;
    float acc[4][4] = {};
    for (int kc = 0; kc < DM; kc += 32) {
        for (int it = 0; it < 8; ++it) {
            int idx = it * 256 + tid;
            int kk = idx >> 6, li = idx & 63;
            As[kk][li] = xb[(kc + kk) * LSEQ + l0 + li];
        }
        for (int it = 0; it < 8; ++it) {
            int idx = it * 256 + tid;
            int jj = idx >> 5, kk = idx & 31;
            Ws[kk][jj] = W_in[(j0 + jj) * DM + kc + kk];
        }
        __syncthreads();
        for (int kk = 0; kk < 32; ++kk) {
            float4 a4 = *(const float4*)&As[kk][ty * 4];
            float4 w4 = *(const float4*)&Ws[kk][tx * 4];
            float av[4] = {a4.x, a4.y, a4.z, a4.w};
            float wv[4] = {w4.x, w4.y, w4.z, w4.w};
            for (int i = 0; i < 4; ++i)
                for (int j = 0; j < 4; ++j) acc[i][j] = fmaf(av[i], wv[j], acc[i][j]);
        }
        __syncthreads();
    }
    for (int i = 0; i < 4; ++i) {
        float4 v = make_float4(acc[i][0], acc[i][1], acc[i][2], acc[i][3]);
        *(float4*)&xi_pre[(size_t)(row0 + ty * 4 + i) * DI + j0 + tx * 4] = v;
    }
}

// ---------------------------------------------------------------------------
// K1b: z at l=255: wave-per-row, coalesced float4 weight loads.
// grid 64: b = bid>>2, jq = bid&3 (128 rows each); 4 waves x 32 rows.
// ---------------------------------------------------------------------------
__global__ __launch_bounds__(256) void k_z255(const float* __restrict__ x,
                                              const float* __restrict__ W_in,
                                              float* __restrict__ z255) {
    __shared__ __align__(16) float xcol[256];
    const int b = blockIdx.x >> 2, jq = blockIdx.x & 3;
    const int tid = threadIdx.x;
    xcol[tid] = x[(size_t)b * DM * LSEQ + tid * LSEQ + 255];
    __syncthreads();
    const int w = tid >> 6, lane = tid & 63;
    float4 xv = *(const float4*)&xcol[lane * 4];
    for (int rr = 0; rr < 32; ++rr) {
        const int j = jq * 128 + w * 32 + rr;
        float4 wv = *(const float4*)&W_in[(size_t)(DI + j) * DM + lane * 4];
        float s = wv.x * xv.x + wv.y * xv.y + wv.z * xv.z + wv.w * xv.w;
        for (int off = 32; off > 0; off >>= 1) s += __shfl_down(s, off);
        if (lane == 0) z255[b * DI + j] = s;
    }
}

// ---------------------------------------------------------------------------
// K2: causal depthwise conv + silu.
// ---------------------------------------------------------------------------
__global__ __launch_bounds__(512) void k_conv(const float* __restrict__ xi_pre,
                                              const float* __restrict__ conv_w,
                                              const float* __restrict__ conv_b,
                                              float* __restrict__ xi) {
    const int bl = blockIdx.x;
    const int l = bl & 255;
    const int d = threadIdx.x;
    float s = conv_b[d];
    for (int k = 0; k < 4; ++k) {
        int ll = l - 3 + k;
        if (ll >= 0) s = fmaf(conv_w[d * 4 + k], xi_pre[(size_t)(bl - 3 + k) * DI + d], s);
    }
    xi[(size_t)bl * DI + d] = silu_f(s);
}

// ---------------------------------------------------------------------------
// K3: dtBC = xi @ W_x^T as LDS-tiled GEMM. M=4096, N=48, K=512.
// 128 blocks x 32 rows; 256 threads = (r=tid>>3, cg=tid&7) -> 6 cols each.
// ---------------------------------------------------------------------------
__global__ __launch_bounds__(256) void k_dtbc(const float* __restrict__ xi,
                                              const float* __restrict__ W_x,
                                              float* __restrict__ dtBC) {
    __shared__ float As[32][65];
    __shared__ float Ws[48][65];
    const int row0 = blockIdx.x * 32;
    const int tid = threadIdx.x;
    const int r = tid >> 3, cg = tid & 7;
    float acc[6] = {};
    for (int kc = 0; kc < DI; kc += 64) {
        for (int it = 0; it < 8; ++it) {
            int idx = it * 256 + tid;
            int rr = idx >> 6, k = idx & 63;
            As[rr][k] = xi[(size_t)(row0 + rr) * DI + kc + k];
        }
        for (int it = 0; it < 12; ++it) {
            int idx = it * 256 + tid;
            int c = idx >> 6, k = idx & 63;
            Ws[c][k] = W_x[(size_t)c * DI + kc + k];
        }
        __syncthreads();
        for (int kk = 0; kk < 64; ++kk) {
            float a = As[r][kk];
            for (int ci = 0; ci < 6; ++ci)
                acc[ci] = fmaf(a, Ws[cg * 6 + ci][kk], acc[ci]);
        }
        __syncthreads();
    }
    for (int ci = 0; ci < 6; ++ci)
        dtBC[(size_t)(row0 + r) * 48 + cg * 6 + ci] = acc[ci];
}

// ---------------------------------------------------------------------------
// K5: chunked scan (unchanged).
// ---------------------------------------------------------------------------
__global__ __launch_bounds__(512) void k_scan_chunk(const float* __restrict__ xi,
                                                    const float* __restrict__ dtBC,
                                                    const float* __restrict__ W_dt,
                                                    const float* __restrict__ b_dt,
                                                    const float* __restrict__ A_log,
                                                    float* __restrict__ Qb,
                                                    float* __restrict__ Sb) {
    const int blk = blockIdx.x;
    const int b = blk >> 3, c = blk & 7;
    const int d = threadIdx.x;
    float Ar[16], Wd[16];
    for (int n = 0; n < 16; ++n) Ar[n] = -__expf(A_log[d * 16 + n]);
    for (int r = 0; r < 16; ++r) Wd[r] = W_dt[d * 16 + r];
    const float bd = b_dt[d];
    float q[16] = {};
    float Ssum = 0.f;
    for (int l = c * 32; l < c * 32 + 32; ++l) {
        const int rl = b * 256 + l;
        const float* dv = dtBC + (size_t)rl * 48;
        float s = bd;
        for (int r = 0; r < 16; ++r) s = fmaf(dv[r], Wd[r], s);
        const float del = softplus_f(s);
        const float u = xi[(size_t)rl * DI + d];
        const float du = del * u;
        Ssum += del;
        for (int n = 0; n < 16; ++n) {
            float dA = __expf(del * Ar[n]);
            q[n] = fmaf(dA, q[n], du * dv[16 + n]);
        }
    }
    float* qo = Qb + ((size_t)blk * DI + d) * 16;
    for (int n = 0; n < 16; ++n) qo[n] = q[n];
    Sb[blk * DI + d] = Ssum;
}

// ---------------------------------------------------------------------------
// K6: compose chunks (unchanged).
// ---------------------------------------------------------------------------
__global__ __launch_bounds__(512) void k_compose(const float* __restrict__ Qb,
                                                 const float* __restrict__ Sb,
                                                 const float* __restrict__ dtBC,
                                                 const float* __restrict__ xi,
                                                 const float* __restrict__ z255,
                                                 const float* __restrict__ A_log,
                                                 const float* __restrict__ Dp,
                                                 float* __restrict__ h_state,
                                                 float* __restrict__ gbuf) {
    const int b = blockIdx.x;
    const int d = threadIdx.x;
    float Ar[16];
    for (int n = 0; n < 16; ++n) Ar[n] = -__expf(A_log[d * 16 + n]);
    float h[16] = {};
    for (int c = 0; c < 8; ++c) {
        const int blk = b * 8 + c;
        const float S = Sb[blk * DI + d];
        const float* qv = Qb + ((size_t)blk * DI + d) * 16;
        for (int n = 0; n < 16; ++n) {
            float P = __expf(S * Ar[n]);
            h[n] = fmaf(P, h[n], qv[n]);
        }
    }
    const float* Cv = dtBC + (size_t)(b * 256 + 255) * 48 + 32;
    float y = 0.f;
    for (int n = 0; n < 16; ++n) y = fmaf(h[n], Cv[n], y);
    const float u = xi[(size_t)(b * 256 + 255) * DI + d];
    y = fmaf(u, Dp[d], y);
    gbuf[b * DI + d] = y * silu_f(z255[b * DI + d]);
    float* ho = h_state + ((size_t)(b * DI + d)) * 16;
    for (int n = 0; n < 16; ++n) ho[n] = h[n];
}

// ---------------------------------------------------------------------------
// K7: persistent generation. 256 blocks = 16 batches x 16 slices (32 d each).
// All weight slices staged in LDS once; per-step GEMVs read LDS only.
// ---------------------------------------------------------------------------
DEV void group_barrier(unsigned* flag, unsigned target) {
    __syncthreads();
    if (threadIdx.x == 0) {
        __hip_atomic_fetch_add(flag, 1u, __ATOMIC_ACQ_REL, __HIP_MEMORY_SCOPE_AGENT);
        while (__hip_atomic_load(flag, __ATOMIC_ACQUIRE, __HIP_MEMORY_SCOPE_AGENT) < target) {
            __builtin_amdgcn_s_sleep(2);
        }
    }
    __syncthreads();
}

__global__ __launch_bounds__(256, 1) void k_gen(
    const float* __restrict__ W_in, const float* __restrict__ conv_w,
    const float* __restrict__ conv_b, const float* __restrict__ W_x,
    const float* __restrict__ W_dt, const float* __restrict__ b_dt,
    const float* __restrict__ A_log, const float* __restrict__ Dp,
    const float* __restrict__ W_out, const float* __restrict__ xi_pre,
    const float* __restrict__ h_state, const float* __restrict__ gbuf0,
    float* __restrict__ o_part, float* __restrict__ dt_part,
    unsigned* __restrict__ bar, float* __restrict__ out) {
    const int bid = blockIdx.x;
    const int b = bid & 15;          // batch; %8 co-locates a group on one XCD
    const int p = bid >> 4;          // slice 0..15
    const int d0 = p * 32;
    const int tid = threadIdx.x;

    // LDS weight slices (bank-conflict-checked pads)
    __shared__ float win_s[64][257];   // rows: 0..31 x-part d0+j, 32..63 z-part
    __shared__ float wout_s[256][33];  // [m][dd]
    __shared__ float wx_s[48][33];     // [r][dd]
    __shared__ float wdt_s[32][17];    // [j][r]
    __shared__ float os[256];
    __shared__ float red[256];
    __shared__ float gs[32], xin[32], zs[32], dtbc[48];
    __shared__ float hist[3][32];

    // ---- stage weights (coalesced, once) ----
    for (int it = 0; it < 64; ++it) {
        int idx = it * 256 + tid;
        int r = idx >> 8, k = idx & 255;
        int jglob = (r < 32) ? (d0 + r) : (DI + d0 + (r - 32));
        win_s[r][k] = W_in[(size_t)jglob * DM + k];
    }
    for (int it = 0; it < 32; ++it) {
        int idx = it * 256 + tid;
        int m = idx >> 5, dd = idx & 31;
        wout_s[m][dd] = W_out[(size_t)m * DI + d0 + dd];
    }
    for (int it = 0; it < 6; ++it) {
        int idx = it * 256 + tid;
        int r = idx >> 5, dd = idx & 31;
        wx_s[r][dd] = W_x[(size_t)r * DI + d0 + dd];
    }
    for (int it = 0; it < 2; ++it) {
        int idx = it * 256 + tid;
        int j = idx >> 4, n = idx & 15;
        wdt_s[j][n] = W_dt[(size_t)(d0 + j) * 16 + n];
    }

    // per-thread constants
    const int dsc = tid >> 3, np = tid & 7, nn = np * 2;   // scan mapping
    const int dg = d0 + dsc;
    float h[2], Ar[2];
    {
        const float* hs = h_state + ((size_t)(b * DI + dg)) * 16 + nn;
        h[0] = hs[0]; h[1] = hs[1];
        Ar[0] = -__expf(A_log[dg * 16 + nn]);
        Ar[1] = -__expf(A_log[dg * 16 + nn + 1]);
    }
    const float bd = b_dt[dg];
    const float Dpv = Dp[dg];
    float cw0 = 0, cw1 = 0, cw2 = 0, cw3 = 0, cb = 0;
    if (tid < 32) {
        const int d = d0 + tid;
        cw0 = conv_w[d * 4 + 0]; cw1 = conv_w[d * 4 + 1];
        cw2 = conv_w[d * 4 + 2]; cw3 = conv_w[d * 4 + 3];
        cb = conv_b[d];
        gs[tid] = gbuf0[b * DI + d];
        for (int k = 0; k < 3; ++k)
            hist[k][tid] = xi_pre[(size_t)(b * 256 + 253 + k) * DI + d];
    }
    __syncthreads();

    unsigned* mybar = bar + b * 32;   // 128B-padded flags
    unsigned nb = 0;

    for (int t = 0; t < TLEN; ++t) {
        // ---- P1: o partial (LDS weights)
        {
            float s = 0.f;
            for (int dd = 0; dd < 32; ++dd) s = fmaf(wout_s[tid][dd], gs[dd], s);
            __hip_atomic_store(&o_part[(b * 16 + p) * 256 + tid], s,
                               __ATOMIC_RELAXED, __HIP_MEMORY_SCOPE_AGENT);
        }
        ++nb; group_barrier(mybar, 16u * nb);

        // ---- P2: reduce o; in-proj; conv; dtbc partials
        {
            float s = 0.f;
            for (int pp = 0; pp < 16; ++pp)
                s += __hip_atomic_load(&o_part[(b * 16 + pp) * 256 + tid],
                                       __ATOMIC_RELAXED, __HIP_MEMORY_SCOPE_AGENT);
            os[tid] = s;
            if (p == 0) out[(b * 256 + tid) * TLEN + t] = s;
        }
        __syncthreads();
        if (t == TLEN - 1) return;

        // in-proj: 64 rows (32 x + 32 z), K=256 split 4 ways; j fast for banks
        {
            const int j = tid & 63, q = tid >> 6;
            float s = 0.f;
            for (int kk = 0; kk < 64; ++kk) s = fmaf(win_s[j][q * 64 + kk], os[q * 64 + kk], s);
            red[tid] = s;
        }
        __syncthreads();
        if (tid < 64) {
            const int j = tid;
            float v = red[j] + red[64 + j] + red[128 + j] + red[192 + j];
            if (j < 32) {
                float xc = cb;
                xc = fmaf(cw0, hist[t % 3][j], xc);
                xc = fmaf(cw1, hist[(t + 1) % 3][j], xc);
                xc = fmaf(cw2, hist[(t + 2) % 3][j], xc);
                xc = fmaf(cw3, v, xc);
                hist[t % 3][j] = v;
                xin[j] = silu_f(xc);
            } else {
                zs[j - 32] = v;
            }
        }
        __syncthreads();
        // dtbc partials: 48 rows x K=32 slice, split 4 ways
        if (tid < 192) {
            const int r = tid >> 2, q = tid & 3;
            float s = 0.f;
            for (int kk = 0; kk < 8; ++kk) s = fmaf(wx_s[r][q * 8 + kk], xin[q * 8 + kk], s);
            red[tid] = s;
        }
        __syncthreads();
        if (tid < 48) {
            float v = red[4 * tid] + red[4 * tid + 1] + red[4 * tid + 2] + red[4 * tid + 3];
            __hip_atomic_store(&dt_part[(b * 16 + p) * 48 + tid], v,
                               __ATOMIC_RELAXED, __HIP_MEMORY_SCOPE_AGENT);
        }
        ++nb; group_barrier(mybar, 16u * nb);

        // ---- P3: reduce dtbc; delta; scan step; gate
        if (tid < 48) {
            float s = 0.f;
            for (int pp = 0; pp < 16; ++pp)
                s += __hip_atomic_load(&dt_part[(b * 16 + pp) * 48 + tid],
                                       __ATOMIC_RELAXED, __HIP_MEMORY_SCOPE_AGENT);
            dtbc[tid] = s;
        }
        __syncthreads();
        {
            float dt_l = bd;
            for (int r = 0; r < 16; ++r) dt_l = fmaf(dtbc[r], wdt_s[dsc][r], dt_l);
            const float del = softplus_f(dt_l);
            const float u = xin[dsc];
            const float du = del * u;
            float y = 0.f;
            for (int j = 0; j < 2; ++j) {
                const int n = nn + j;
                float dA = __expf(del * Ar[j]);
                h[j] = fmaf(dA, h[j], du * dtbc[16 + n]);
                y = fmaf(h[j], dtbc[32 + n], y);
            }
            y += __shfl_xor(y, 1);
            y += __shfl_xor(y, 2);
            y += __shfl_xor(y, 4);
            if (np == 0) {
                float yt = fmaf(u, Dpv, y);
                gs[dsc] = yt * silu_f(zs[dsc]);
            }
        }
        __syncthreads();
    }
}

// ---------------------------------------------------------------------------
extern "C" void kernel_launch(void* const* d_in, const int* in_sizes, int n_in,
                              void* d_out, int out_size, void* d_ws, size_t ws_size,
                              hipStream_t stream) {
    const float* x      = (const float*)d_in[0];
    const float* W_in   = (const float*)d_in[1];
    const float* conv_w = (const float*)d_in[2];
    const float* conv_b = (const float*)d_in[3];
    const float* W_x    = (const float*)d_in[4];
    const float* W_dt   = (const float*)d_in[5];
    const float* b_dt   = (const float*)d_in[6];
    const float* A_log  = (const float*)d_in[7];
    const float* Dp     = (const float*)d_in[8];
    const float* W_out  = (const float*)d_in[9];
    float* out = (float*)d_out;

    float* base = (float*)d_ws;
    size_t off = 0;
    auto alloc = [&](size_t n) { float* pp = base + off; off += (n + 15) & ~(size_t)15; return pp; };
    unsigned* bar   = (unsigned*)alloc(16 * 32);
    float* o_part   = alloc(16 * 16 * 256);
    float* dt_part  = alloc(16 * 16 * 48);
    float* gbuf     = alloc(16 * 512);
    float* h_state  = alloc((size_t)16 * 512 * 16);
    float* z255     = alloc(16 * 512);
    float* dtBC     = alloc((size_t)4096 * 48);
    float* Sb       = alloc((size_t)128 * 512);
    float* Qb       = alloc((size_t)128 * 512 * 16);
    float* xi_pre   = alloc((size_t)4096 * 512);
    float* xi       = alloc((size_t)4096 * 512);

    hipMemsetAsync(bar, 0, 16 * 32 * sizeof(unsigned), stream);
    hipLaunchKernelGGL(k_inproj, dim3(8, 64), dim3(256), 0, stream, x, W_in, xi_pre);
    hipLaunchKernelGGL(k_z255, dim3(64), dim3(256), 0, stream, x, W_in, z255);
    hipLaunchKernelGGL(k_conv, dim3(4096), dim3(512), 0, stream, xi_pre, conv_w, conv_b, xi);
    hipLaunchKernelGGL(k_dtbc, dim3(128), dim3(256), 0, stream, xi, W_x, dtBC);
    hipLaunchKernelGGL(k_scan_chunk, dim3(128), dim3(512), 0, stream,
                       xi, dtBC, W_dt, b_dt, A_log, Qb, Sb);
    hipLaunchKernelGGL(k_compose, dim3(16), dim3(512), 0, stream,
                       Qb, Sb, dtBC, xi, z255, A_log, Dp, h_state, gbuf);
    hipLaunchKernelGGL(k_gen, dim3(256), dim3(256), 0, stream,
                       W_in, conv_w, conv_b, W_x, W_dt, b_dt, A_log, Dp, W_out,
                       xi_pre, h_state, gbuf, o_part, dt_part, bar, out);
}

// Round 3
// 358.314 us; speedup vs baseline: 1.1850x; 1.1850x over previous
//
#include <hip/hip_runtime.h>
#include <cmath>

#define DEV __device__ __forceinline__

constexpr int B_SZ = 16;
constexpr int LSEQ = 256;
constexpr int DM   = 256;   // d_model
constexpr int DI   = 512;   // d_inner
constexpr int TLEN = 16;

DEV float silu_f(float x)     { return x / (1.f + __expf(-x)); }
DEV float softplus_f(float x) { return log1pf(__expf(x)); }

// ---------------------------------------------------------------------------
// K0: fold W_c[j][d] = sum_m W_in[j][m] * W_out[m][d].  (1024 x 512, K=256)
// ---------------------------------------------------------------------------
__global__ __launch_bounds__(256) void k_fold(const float* __restrict__ W_in,
                                              const float* __restrict__ W_out,
                                              float* __restrict__ Wc) {
    __shared__ float As[32][68];   // [kk][jj]
    __shared__ float Bs[32][68];   // [kk][dd]
    const int j0 = blockIdx.y * 64;
    const int d0 = blockIdx.x * 64;
    const int tid = threadIdx.x;
    const int ty = tid >> 4, tx = tid & 15;
    float acc[4][4] = {};
    for (int kc = 0; kc < DM; kc += 32) {
        for (int it = 0; it < 8; ++it) {
            int idx = it * 256 + tid;
            int jj = idx >> 5, kk = idx & 31;
            As[kk][jj] = W_in[(size_t)(j0 + jj) * DM + kc + kk];
        }
        for (int it = 0; it < 8; ++it) {
            int idx = it * 256 + tid;
            int kk = idx >> 6, dd = idx & 63;
            Bs[kk][dd] = W_out[(size_t)(kc + kk) * DI + d0 + dd];
        }
        __syncthreads();
        for (int kk = 0; kk < 32; ++kk) {
            float4 a4 = *(const float4*)&As[kk][ty * 4];
            float4 b4 = *(const float4*)&Bs[kk][tx * 4];
            float av[4] = {a4.x, a4.y, a4.z, a4.w};
            float bv[4] = {b4.x, b4.y, b4.z, b4.w};
            for (int i = 0; i < 4; ++i)
                for (int j = 0; j < 4; ++j) acc[i][j] = fmaf(av[i], bv[j], acc[i][j]);
        }
        __syncthreads();
    }
    for (int i = 0; i < 4; ++i) {
        float4 v = make_float4(acc[i][0], acc[i][1], acc[i][2], acc[i][3]);
        *(float4*)&Wc[(size_t)(j0 + ty * 4 + i) * DI + d0 + tx * 4] = v;
    }
}

// ---------------------------------------------------------------------------
// K1: in-projection (x part): xi_pre[(b*L+l)*DI + j] = sum_k x[b,k,l]*W_in[j,k]
// ---------------------------------------------------------------------------
__global__ __launch_bounds__(256) void k_inproj(const float* __restrict__ x,
                                                const float* __restrict__ W_in,
                                                float* __restrict__ xi_pre) {
    __shared__ float As[32][68];
    __shared__ float Ws[32][68];
    const int by = blockIdx.y, bx = blockIdx.x;
    const int row0 = by * 64;
    const int b = row0 >> 8, l0 = row0 & 255;
    const int j0 = bx * 64;
    const int tid = threadIdx.x;
    const int ty = tid >> 4, tx = tid & 15;
    const float* xb = x + (size_t)b * DM * LSEQ;
    float acc[4][4] = {};
    for (int kc = 0; kc < DM; kc += 32) {
        for (int it = 0; it < 8; ++it) {
            int idx = it * 256 + tid;
            int kk = idx >> 6, li = idx & 63;
            As[kk][li] = xb[(kc + kk) * LSEQ + l0 + li];
        }
        for (int it = 0; it < 8; ++it) {
            int idx = it * 256 + tid;
            int jj = idx >> 5, kk = idx & 31;
            Ws[kk][jj] = W_in[(size_t)(j0 + jj) * DM + kc + kk];
        }
        __syncthreads();
        for (int kk = 0; kk < 32; ++kk) {
            float4 a4 = *(const float4*)&As[kk][ty * 4];
            float4 w4 = *(const float4*)&Ws[kk][tx * 4];
            float av[4] = {a4.x, a4.y, a4.z, a4.w};
            float wv[4] = {w4.x, w4.y, w4.z, w4.w};
            for (int i = 0; i < 4; ++i)
                for (int j = 0; j < 4; ++j) acc[i][j] = fmaf(av[i], wv[j], acc[i][j]);
        }
        __syncthreads();
    }
    for (int i = 0; i < 4; ++i) {
        float4 v = make_float4(acc[i][0], acc[i][1], acc[i][2], acc[i][3]);
        *(float4*)&xi_pre[(size_t)(row0 + ty * 4 + i) * DI + j0 + tx * 4] = v;
    }
}

// ---------------------------------------------------------------------------
// K1b: z at l=255 (wave-per-row, coalesced float4 weight loads)
// ---------------------------------------------------------------------------
__global__ __launch_bounds__(256) void k_z255(const float* __restrict__ x,
                                              const float* __restrict__ W_in,
                                              float* __restrict__ z255) {
    __shared__ __align__(16) float xcol[256];
    const int b = blockIdx.x >> 2, jq = blockIdx.x & 3;
    const int tid = threadIdx.x;
    xcol[tid] = x[(size_t)b * DM * LSEQ + tid * LSEQ + 255];
    __syncthreads();
    const int w = tid >> 6, lane = tid & 63;
    float4 xv = *(const float4*)&xcol[lane * 4];
    for (int rr = 0; rr < 32; ++rr) {
        const int j = jq * 128 + w * 32 + rr;
        float4 wv = *(const float4*)&W_in[(size_t)(DI + j) * DM + lane * 4];
        float s = wv.x * xv.x + wv.y * xv.y + wv.z * xv.z + wv.w * xv.w;
        for (int off = 32; off > 0; off >>= 1) s += __shfl_down(s, off);
        if (lane == 0) z255[b * DI + j] = s;
    }
}

// ---------------------------------------------------------------------------
// K3: dtBC = silu(conv(xi_pre)) @ W_x^T, conv inlined. M=4096, N=48, K=512.
// ---------------------------------------------------------------------------
__global__ __launch_bounds__(256) void k_dtbc(const float* __restrict__ xi_pre,
                                              const float* __restrict__ conv_w,
                                              const float* __restrict__ conv_b,
                                              const float* __restrict__ W_x,
                                              float* __restrict__ dtBC) {
    __shared__ float A2[35][65];
    __shared__ float As[32][65];
    __shared__ float Ws[48][65];
    __shared__ float cw_s[64][5];
    const int row0 = blockIdx.x * 32;
    const int b = row0 >> 8, l0 = row0 & 255;
    const int tid = threadIdx.x;
    const int r = tid >> 3, cg = tid & 7;
    float acc[6] = {};
    for (int kc = 0; kc < DI; kc += 64) {
        for (int it = 0; it < 9; ++it) {
            int idx = it * 256 + tid;
            if (idx < 2240) {
                int rr = idx >> 6, k = idx & 63;
                int l = l0 + rr - 3;
                A2[rr][k] = (l >= 0) ? xi_pre[(size_t)(b * 256 + l) * DI + kc + k] : 0.f;
            }
        }
        if (tid < 64) {
            for (int j = 0; j < 4; ++j) cw_s[tid][j] = conv_w[(kc + tid) * 4 + j];
            cw_s[tid][4] = conv_b[kc + tid];
        }
        for (int it = 0; it < 12; ++it) {
            int idx = it * 256 + tid;
            int c = idx >> 6, k = idx & 63;
            Ws[c][k] = W_x[(size_t)c * DI + kc + k];
        }
        __syncthreads();
        for (int it = 0; it < 8; ++it) {
            int idx = it * 256 + tid;
            int rr = idx >> 6, k = idx & 63;
            float s = cw_s[k][4];
            for (int j = 0; j < 4; ++j) s = fmaf(cw_s[k][j], A2[rr + j][k], s);
            As[rr][k] = silu_f(s);
        }
        __syncthreads();
        for (int kk = 0; kk < 64; ++kk) {
            float a = As[r][kk];
            for (int ci = 0; ci < 6; ++ci)
                acc[ci] = fmaf(a, Ws[cg * 6 + ci][kk], acc[ci]);
        }
        __syncthreads();
    }
    for (int ci = 0; ci < 6; ++ci)
        dtBC[(size_t)(row0 + r) * 48 + cg * 6 + ci] = acc[ci];
}

// ---------------------------------------------------------------------------
// K5: chunked scan, conv inlined (rolling window).
// ---------------------------------------------------------------------------
__global__ __launch_bounds__(512) void k_scan_chunk(const float* __restrict__ xi_pre,
                                                    const float* __restrict__ conv_w,
                                                    const float* __restrict__ conv_b,
                                                    const float* __restrict__ dtBC,
                                                    const float* __restrict__ W_dt,
                                                    const float* __restrict__ b_dt,
                                                    const float* __restrict__ A_log,
                                                    float* __restrict__ Qb,
                                                    float* __restrict__ Sb) {
    const int blk = blockIdx.x;
    const int b = blk >> 3, c = blk & 7;
    const int d = threadIdx.x;
    float Ar[16], Wd[16];
    for (int n = 0; n < 16; ++n) Ar[n] = -__expf(A_log[d * 16 + n]);
    for (int r = 0; r < 16; ++r) Wd[r] = W_dt[d * 16 + r];
    const float bd = b_dt[d];
    const float c0 = conv_w[d * 4 + 0], c1 = conv_w[d * 4 + 1];
    const float c2 = conv_w[d * 4 + 2], c3 = conv_w[d * 4 + 3];
    const float cbv = conv_b[d];
    const int lbase = c * 32;
    float p0, p1, p2;
    {
        int l;
        l = lbase - 3; p0 = (l >= 0) ? xi_pre[(size_t)(b * 256 + l) * DI + d] : 0.f;
        l = lbase - 2; p1 = (l >= 0) ? xi_pre[(size_t)(b * 256 + l) * DI + d] : 0.f;
        l = lbase - 1; p2 = (l >= 0) ? xi_pre[(size_t)(b * 256 + l) * DI + d] : 0.f;
    }
    float q[16] = {};
    float Ssum = 0.f;
    for (int l = lbase; l < lbase + 32; ++l) {
        const int rl = b * 256 + l;
        const float v = xi_pre[(size_t)rl * DI + d];
        const float u = silu_f(cbv + c0 * p0 + c1 * p1 + c2 * p2 + c3 * v);
        p0 = p1; p1 = p2; p2 = v;
        const float* dv = dtBC + (size_t)rl * 48;
        float s = bd;
        for (int r = 0; r < 16; ++r) s = fmaf(dv[r], Wd[r], s);
        const float del = softplus_f(s);
        const float du = del * u;
        Ssum += del;
        for (int n = 0; n < 16; ++n) {
            float dA = __expf(del * Ar[n]);
            q[n] = fmaf(dA, q[n], du * dv[16 + n]);
        }
    }
    float* qo = Qb + ((size_t)blk * DI + d) * 16;
    for (int n = 0; n < 16; ++n) qo[n] = q[n];
    Sb[blk * DI + d] = Ssum;
}

// ---------------------------------------------------------------------------
// K6: compose chunks -> h at 255, gate -> gbuf; conv inlined for u.
// ---------------------------------------------------------------------------
__global__ __launch_bounds__(512) void k_compose(const float* __restrict__ Qb,
                                                 const float* __restrict__ Sb,
                                                 const float* __restrict__ dtBC,
                                                 const float* __restrict__ xi_pre,
                                                 const float* __restrict__ conv_w,
                                                 const float* __restrict__ conv_b,
                                                 const float* __restrict__ z255,
                                                 const float* __restrict__ A_log,
                                                 const float* __restrict__ Dp,
                                                 float* __restrict__ h_state,
                                                 float* __restrict__ gbuf) {
    const int b = blockIdx.x;
    const int d = threadIdx.x;
    float Ar[16];
    for (int n = 0; n < 16; ++n) Ar[n] = -__expf(A_log[d * 16 + n]);
    float h[16] = {};
    for (int c = 0; c < 8; ++c) {
        const int blk = b * 8 + c;
        const float S = Sb[blk * DI + d];
        const float* qv = Qb + ((size_t)blk * DI + d) * 16;
        for (int n = 0; n < 16; ++n) {
            float P = __expf(S * Ar[n]);
            h[n] = fmaf(P, h[n], qv[n]);
        }
    }
    const float* Cv = dtBC + (size_t)(b * 256 + 255) * 48 + 32;
    float y = 0.f;
    for (int n = 0; n < 16; ++n) y = fmaf(h[n], Cv[n], y);
    float u;
    {
        float pv[4];
        for (int k = 0; k < 4; ++k) pv[k] = xi_pre[(size_t)(b * 256 + 252 + k) * DI + d];
        float s = conv_b[d];
        for (int k = 0; k < 4; ++k) s = fmaf(conv_w[d * 4 + k], pv[k], s);
        u = silu_f(s);
    }
    y = fmaf(u, Dp[d], y);
    gbuf[b * DI + d] = y * silu_f(z255[b * DI + d]);
    float* ho = h_state + ((size_t)(b * DI + d)) * 16;
    for (int n = 0; n < 16; ++n) ho[n] = h[n];
}

// ---------------------------------------------------------------------------
// K7: persistent generation. 256 blocks = 16 batches x 16 slices, 512 thr.
// ONE exchange per step (flag-based, no RMW): post xin/z slices + dtbc
// partials; replicated scan gives every block the full gs locally.
// ---------------------------------------------------------------------------
__global__ __launch_bounds__(512, 1) void k_gen(
    const float* __restrict__ Wc, const float* __restrict__ W_out,
    const float* __restrict__ W_x, const float* __restrict__ W_dt,
    const float* __restrict__ conv_w, const float* __restrict__ conv_b,
    const float* __restrict__ b_dt, const float* __restrict__ A_log,
    const float* __restrict__ Dp, const float* __restrict__ xi_pre,
    const float* __restrict__ h_state, const float* __restrict__ gbuf0,
    float* __restrict__ xbuf, unsigned* __restrict__ flags,
    float* __restrict__ out) {
    const int bid = blockIdx.x;
    const int b = bid & 15;     // batch (16 blocks of a batch share bid%8 -> XCD)
    const int p = bid >> 4;     // slice 0..15
    const int tid = threadIdx.x;

    __shared__ float wc_s[64][513];   // rows 0..31 x-part, 32..63 z-part (K=512)
    __shared__ float wx_s[48][33];    // W_x column-slice [48][32]
    __shared__ float gs_s[512];
    __shared__ float xin_s[512];
    __shared__ float zs_s[512];
    __shared__ float dpart[16][49];
    __shared__ float dtbc_s[48];
    __shared__ float red8[8][65];
    __shared__ float hist[3][32];
    __shared__ float post_s[112];     // [0,32): xin own  [32,64): z own  [64,112): dtbc partial

    // ---- stage W_c row-slice (coalesced float4 loads) ----
    for (int i = 0; i < 16; ++i) {
        int flat = i * 512 + tid;            // float4 index
        int rr = flat >> 7;
        int c4 = (flat & 127) * 4;
        int gr = (rr < 32) ? (p * 32 + rr) : (DI + p * 32 + (rr - 32));
        float4 v = *(const float4*)&Wc[(size_t)gr * DI + c4];
        wc_s[rr][c4 + 0] = v.x; wc_s[rr][c4 + 1] = v.y;
        wc_s[rr][c4 + 2] = v.z; wc_s[rr][c4 + 3] = v.w;
    }
    for (int i = 0; i < 3; ++i) {
        int flat = i * 512 + tid;            // 1536 elems
        int rr = flat >> 5, cc = flat & 31;
        wx_s[rr][cc] = W_x[(size_t)rr * DI + p * 32 + cc];
    }
    // W_out row-slice in registers: row = p*16 + (tid>>5), cols (tid&31) + 32j
    const int orow = p * 16 + (tid >> 5), osub = tid & 31;
    float wout[16];
    #pragma unroll
    for (int j = 0; j < 16; ++j) wout[j] = W_out[(size_t)orow * DI + osub + 32 * j];

    // per-thread scan state (d = tid)
    float wdt[16], Ar[16], h[16];
    {
        const float4* wp = (const float4*)&W_dt[tid * 16];
        const float4* ap = (const float4*)&A_log[tid * 16];
        const float4* hp = (const float4*)&h_state[((size_t)(b * DI + tid)) * 16];
        #pragma unroll
        for (int i = 0; i < 4; ++i) {
            float4 wv = wp[i], av = ap[i], hv = hp[i];
            wdt[4*i+0]=wv.x; wdt[4*i+1]=wv.y; wdt[4*i+2]=wv.z; wdt[4*i+3]=wv.w;
            Ar[4*i+0]=-__expf(av.x); Ar[4*i+1]=-__expf(av.y);
            Ar[4*i+2]=-__expf(av.z); Ar[4*i+3]=-__expf(av.w);
            h[4*i+0]=hv.x; h[4*i+1]=hv.y; h[4*i+2]=hv.z; h[4*i+3]=hv.w;
        }
    }
    const float bd = b_dt[tid];
    const float Dpv = Dp[tid];
    float cw0 = 0, cw1 = 0, cw2 = 0, cw3 = 0, cb = 0;
    if (tid < 32) {
        const int d = p * 32 + tid;
        cw0 = conv_w[d * 4 + 0]; cw1 = conv_w[d * 4 + 1];
        cw2 = conv_w[d * 4 + 2]; cw3 = conv_w[d * 4 + 3];
        cb  = conv_b[d];
        for (int k = 0; k < 3; ++k)
            hist[k][tid] = xi_pre[(size_t)(b * 256 + 253 + k) * DI + d];
    }
    gs_s[tid] = gbuf0[b * DI + tid];
    __syncthreads();

    for (int t = 0; t < TLEN; ++t) {
        if (t < TLEN - 1) {
            // preconv GEMV: 64 rows x 512; r fast across lanes (2-way LDS only)
            {
                const int r = tid & 63, sub = tid >> 6;
                const float* wrow = &wc_s[r][sub * 64];
                const float* gv = &gs_s[sub * 64];
                float s = 0.f;
                #pragma unroll
                for (int k = 0; k < 64; ++k) s = fmaf(wrow[k], gv[k], s);
                red8[sub][r] = s;
            }
            __syncthreads();
            if (tid < 64) {
                float v = 0.f;
                #pragma unroll
                for (int ss = 0; ss < 8; ++ss) v += red8[ss][tid];
                if (tid < 32) {
                    float xc = cb;
                    xc = fmaf(cw0, hist[t % 3][tid], xc);
                    xc = fmaf(cw1, hist[(t + 1) % 3][tid], xc);
                    xc = fmaf(cw2, hist[(t + 2) % 3][tid], xc);
                    xc = fmaf(cw3, v, xc);
                    hist[t % 3][tid] = v;
                    post_s[tid] = silu_f(xc);
                } else {
                    post_s[tid] = v;   // raw z
                }
            }
            __syncthreads();
            // dtbc partial: 48 rows x 32 own-xin cols
            if (tid < 384) {
                const int r = tid >> 3, sub = tid & 7;
                const float* wr = &wx_s[r][sub * 4];
                const float* xv = &post_s[sub * 4];
                float s = wr[0]*xv[0] + wr[1]*xv[1] + wr[2]*xv[2] + wr[3]*xv[3];
                s += __shfl_down(s, 4); s += __shfl_down(s, 2); s += __shfl_down(s, 1);
                if (sub == 0) post_s[64 + r] = s;
            }
            __syncthreads();
            if (tid < 112) {
                float* slot = xbuf + ((size_t)((b * 16 + p) * 2 + (t & 1))) * 128;
                __hip_atomic_store(&slot[tid], post_s[tid],
                                   __ATOMIC_RELAXED, __HIP_MEMORY_SCOPE_AGENT);
            }
            __syncthreads();   // drains posts (vmcnt(0) before barrier)
            if (tid == 256)
                __hip_atomic_store(&flags[(b * 16 + p) * 16], (unsigned)(t + 1),
                                   __ATOMIC_RELEASE, __HIP_MEMORY_SCOPE_AGENT);
        }
        // output token t (overlaps other blocks' posting)
        {
            float s = 0.f;
            #pragma unroll
            for (int j = 0; j < 16; ++j) s = fmaf(wout[j], gs_s[osub + 32 * j], s);
            s += __shfl_down(s, 16); s += __shfl_down(s, 8);
            s += __shfl_down(s, 4);  s += __shfl_down(s, 2); s += __shfl_down(s, 1);
            if (osub == 0) out[(size_t)(b * 256 + orow) * TLEN + t] = s;
        }
        if (t == TLEN - 1) return;

        // poll 16 flags in parallel (own cache line each, no RMW)
        if (tid < 16) {
            while (__hip_atomic_load(&flags[(b * 16 + tid) * 16],
                                     __ATOMIC_ACQUIRE, __HIP_MEMORY_SCOPE_AGENT)
                   < (unsigned)(t + 1))
                __builtin_amdgcn_s_sleep(1);
        }
        __syncthreads();
        // gather 16 x 112 floats
        for (int i = 0; i < 4; ++i) {
            int idx = i * 512 + tid;               // 0..2047
            int q = idx >> 7, pos = idx & 127;
            if (pos < 112) {
                float v = __hip_atomic_load(
                    xbuf + ((size_t)((b * 16 + q) * 2 + (t & 1))) * 128 + pos,
                    __ATOMIC_RELAXED, __HIP_MEMORY_SCOPE_AGENT);
                if (pos < 32)      xin_s[q * 32 + pos] = v;
                else if (pos < 64) zs_s[q * 32 + pos - 32] = v;
                else               dpart[q][pos - 64] = v;
            }
        }
        __syncthreads();
        if (tid < 48) {
            float s = 0.f;
            #pragma unroll
            for (int q = 0; q < 16; ++q) s += dpart[q][tid];
            dtbc_s[tid] = s;
        }
        __syncthreads();
        // replicated scan step (d = tid)
        {
            float dt_l = bd;
            #pragma unroll
            for (int r = 0; r < 16; ++r) dt_l = fmaf(dtbc_s[r], wdt[r], dt_l);
            const float del = softplus_f(dt_l);
            const float u = xin_s[tid];
            const float du = del * u;
            float y = 0.f;
            #pragma unroll
            for (int n = 0; n < 16; ++n) {
                float dA = __expf(del * Ar[n]);
                h[n] = fmaf(dA, h[n], du * dtbc_s[16 + n]);
                y = fmaf(h[n], dtbc_s[32 + n], y);
            }
            y = fmaf(u, Dpv, y);
            gs_s[tid] = y * silu_f(zs_s[tid]);
        }
        __syncthreads();
    }
}

// ---------------------------------------------------------------------------
extern "C" void kernel_launch(void* const* d_in, const int* in_sizes, int n_in,
                              void* d_out, int out_size, void* d_ws, size_t ws_size,
                              hipStream_t stream) {
    const float* x      = (const float*)d_in[0];
    const float* W_in   = (const float*)d_in[1];
    const float* conv_w = (const float*)d_in[2];
    const float* conv_b = (const float*)d_in[3];
    const float* W_x    = (const float*)d_in[4];
    const float* W_dt   = (const float*)d_in[5];
    const float* b_dt   = (const float*)d_in[6];
    const float* A_log  = (const float*)d_in[7];
    const float* Dp     = (const float*)d_in[8];
    const float* W_out  = (const float*)d_in[9];
    float* out = (float*)d_out;

    float* base = (float*)d_ws;
    size_t off = 0;
    auto alloc = [&](size_t n) { float* pp = base + off; off += (n + 15) & ~(size_t)15; return pp; };
    unsigned* flags = (unsigned*)alloc(256 * 16);
    float* xbuf     = alloc((size_t)16 * 16 * 2 * 128);
    float* gbuf     = alloc(16 * 512);
    float* h_state  = alloc((size_t)16 * 512 * 16);
    float* z255     = alloc(16 * 512);
    float* dtBC     = alloc((size_t)4096 * 48);
    float* Sb       = alloc((size_t)128 * 512);
    float* Qb       = alloc((size_t)128 * 512 * 16);
    float* xi_pre   = alloc((size_t)4096 * 512);
    float* Wc       = alloc((size_t)1024 * 512);

    hipMemsetAsync(flags, 0, 256 * 16 * sizeof(unsigned), stream);
    hipLaunchKernelGGL(k_fold, dim3(8, 16), dim3(256), 0, stream, W_in, W_out, Wc);
    hipLaunchKernelGGL(k_inproj, dim3(8, 64), dim3(256), 0, stream, x, W_in, xi_pre);
    hipLaunchKernelGGL(k_z255, dim3(64), dim3(256), 0, stream, x, W_in, z255);
    hipLaunchKernelGGL(k_dtbc, dim3(128), dim3(256), 0, stream,
                       xi_pre, conv_w, conv_b, W_x, dtBC);
    hipLaunchKernelGGL(k_scan_chunk, dim3(128), dim3(512), 0, stream,
                       xi_pre, conv_w, conv_b, dtBC, W_dt, b_dt, A_log, Qb, Sb);
    hipLaunchKernelGGL(k_compose, dim3(16), dim3(512), 0, stream,
                       Qb, Sb, dtBC, xi_pre, conv_w, conv_b, z255, A_log, Dp,
                       h_state, gbuf);
    hipLaunchKernelGGL(k_gen, dim3(256), dim3(512), 0, stream,
                       Wc, W_out, W_x, W_dt, conv_w, conv_b, b_dt, A_log, Dp,
                       xi_pre, h_state, gbuf, xbuf, flags, out);
}

// Round 5
// 357.318 us; speedup vs baseline: 1.1883x; 1.0028x over previous
//
#include <hip/hip_runtime.h>
#include <cmath>

#define DEV __device__ __forceinline__

constexpr int B_SZ = 16;
constexpr int LSEQ = 256;
constexpr int DM   = 256;   // d_model
constexpr int DI   = 512;   // d_inner
constexpr int TLEN = 16;

DEV float silu_f(float x)     { return x / (1.f + __expf(-x)); }
DEV float softplus_f(float x) { return log1pf(__expf(x)); }

// ---------------------------------------------------------------------------
// kA: blocks [0,128): fold WcT[k][newc] = (W_in·W_out)^T in gen-sliced layout
//     blocks [128,640): in-projection xi_pre = x^T @ W_in(x-part)^T
// ---------------------------------------------------------------------------
__global__ __launch_bounds__(256) void k_prefill_a(const float* __restrict__ x,
                                                   const float* __restrict__ W_in,
                                                   const float* __restrict__ W_out,
                                                   float* __restrict__ WcT,
                                                   float* __restrict__ xi_pre) {
    __shared__ float smem[2][32][68];
    const int tid = threadIdx.x;
    const int ty = tid >> 4, tx = tid & 15;
    float acc[4][4] = {};
    if (blockIdx.x < 128) {
        // ---- fold: tile j0 (Wc row) x d0 (Wc col) ----
        const int j0 = (int)(blockIdx.x & 15) * 64;
        const int d0 = (int)(blockIdx.x >> 4) * 64;
        float (*As)[68] = smem[0];
        float (*Bs)[68] = smem[1];
        for (int kc = 0; kc < DM; kc += 32) {
            for (int it = 0; it < 8; ++it) {
                int idx = it * 256 + tid;
                int jj = idx >> 5, kk = idx & 31;
                As[kk][jj] = W_in[(size_t)(j0 + jj) * DM + kc + kk];
            }
            for (int it = 0; it < 8; ++it) {
                int idx = it * 256 + tid;
                int kk = idx >> 6, dd = idx & 63;
                Bs[kk][dd] = W_out[(size_t)(kc + kk) * DI + d0 + dd];
            }
            __syncthreads();
            for (int kk = 0; kk < 32; ++kk) {
                float4 a4 = *(const float4*)&As[kk][ty * 4];
                float4 b4 = *(const float4*)&Bs[kk][tx * 4];
                float av[4] = {a4.x, a4.y, a4.z, a4.w};
                float bv[4] = {b4.x, b4.y, b4.z, b4.w};
                for (int i = 0; i < 4; ++i)
                    for (int j = 0; j < 4; ++j) acc[i][j] = fmaf(av[i], bv[j], acc[i][j]);
            }
            __syncthreads();
        }
        // transpose via LDS, then store rows=k(d), cols=gen-sliced j
        float (*Cs)[65] = (float(*)[65])&smem[0][0][0];
        for (int i = 0; i < 4; ++i)
            for (int j = 0; j < 4; ++j)
                Cs[ty * 4 + i][tx * 4 + j] = acc[i][j];
        __syncthreads();
        const int dr = tid >> 2, jq = tid & 3;
        for (int ii = 0; ii < 4; ++ii) {
            int jl = jq * 16 + ii * 4;
            int jg = j0 + jl;
            int newc;
            if (jg < DI) newc = (jg >> 5) * 64 + (jg & 31);
            else { int jz = jg - DI; newc = (jz >> 5) * 64 + 32 + (jz & 31); }
            float4 v = make_float4(Cs[jl][dr], Cs[jl + 1][dr], Cs[jl + 2][dr], Cs[jl + 3][dr]);
            *(float4*)&WcT[(size_t)(d0 + dr) * 1024 + newc] = v;
        }
    } else {
        // ---- inproj tile ----
        const int bid2 = (int)blockIdx.x - 128;
        const int bx = bid2 & 7, by = bid2 >> 3;
        const int row0 = by * 64;
        const int b = row0 >> 8, l0 = row0 & 255;
        const int j0 = bx * 64;
        float (*As)[68] = smem[0];
        float (*Ws)[68] = smem[1];
        const float* xb = x + (size_t)b * DM * LSEQ;
        for (int kc = 0; kc < DM; kc += 32) {
            for (int it = 0; it < 8; ++it) {
                int idx = it * 256 + tid;
                int kk = idx >> 6, li = idx & 63;
                As[kk][li] = xb[(kc + kk) * LSEQ + l0 + li];
            }
            for (int it = 0; it < 8; ++it) {
                int idx = it * 256 + tid;
                int jj = idx >> 5, kk = idx & 31;
                Ws[kk][jj] = W_in[(size_t)(j0 + jj) * DM + kc + kk];
            }
            __syncthreads();
            for (int kk = 0; kk < 32; ++kk) {
                float4 a4 = *(const float4*)&As[kk][ty * 4];
                float4 w4 = *(const float4*)&Ws[kk][tx * 4];
                float av[4] = {a4.x, a4.y, a4.z, a4.w};
                float wv[4] = {w4.x, w4.y, w4.z, w4.w};
                for (int i = 0; i < 4; ++i)
                    for (int j = 0; j < 4; ++j) acc[i][j] = fmaf(av[i], wv[j], acc[i][j]);
            }
            __syncthreads();
        }
        for (int i = 0; i < 4; ++i) {
            float4 v = make_float4(acc[i][0], acc[i][1], acc[i][2], acc[i][3]);
            *(float4*)&xi_pre[(size_t)(row0 + ty * 4 + i) * DI + j0 + tx * 4] = v;
        }
    }
}

// ---------------------------------------------------------------------------
// kB: fused conv+silu -> dtBC GEMM -> chunked scan, per (b, chunk).
// 128 blocks x 512 threads. Emits Qb/Sb; chunk 7 also emits dtBC row 255.
// ---------------------------------------------------------------------------
__global__ __launch_bounds__(512) void k_prefill_b(const float* __restrict__ xi_pre,
                                                   const float* __restrict__ conv_w,
                                                   const float* __restrict__ conv_b,
                                                   const float* __restrict__ W_x,
                                                   const float* __restrict__ W_dt,
                                                   const float* __restrict__ b_dt,
                                                   const float* __restrict__ A_log,
                                                   float* __restrict__ Qb,
                                                   float* __restrict__ Sb,
                                                   float* __restrict__ dtBC255) {
    __shared__ float As[32][516];
    __shared__ float Ws[48][129];
    __shared__ float dt_s[32][49];
    const int blk = blockIdx.x;
    const int b = blk >> 3, c = blk & 7;
    const int d = threadIdx.x;
    const int l0 = c * 32;
    // phase 1: conv + silu into As
    {
        const float c0 = conv_w[d * 4 + 0], c1 = conv_w[d * 4 + 1];
        const float c2 = conv_w[d * 4 + 2], c3 = conv_w[d * 4 + 3];
        const float cbv = conv_b[d];
        float p0, p1, p2;
        int l;
        l = l0 - 3; p0 = (l >= 0) ? xi_pre[(size_t)(b * 256 + l) * DI + d] : 0.f;
        l = l0 - 2; p1 = (l >= 0) ? xi_pre[(size_t)(b * 256 + l) * DI + d] : 0.f;
        l = l0 - 1; p2 = (l >= 0) ? xi_pre[(size_t)(b * 256 + l) * DI + d] : 0.f;
        for (int ll = 0; ll < 32; ++ll) {
            float v = xi_pre[(size_t)(b * 256 + l0 + ll) * DI + d];
            As[ll][d] = silu_f(cbv + c0 * p0 + c1 * p1 + c2 * p2 + c3 * v);
            p0 = p1; p1 = p2; p2 = v;
        }
    }
    __syncthreads();
    // phase 2: dt_s[l][r] = sum_d As[l][d] * W_x[r][d]
    {
        const int lr = d >> 4, rg = d & 15;
        float acc[3] = {};
        for (int kc = 0; kc < 4; ++kc) {
            for (int it = 0; it < 12; ++it) {
                int idx = it * 512 + d;
                int rr = idx >> 7, k = idx & 127;
                Ws[rr][k] = W_x[(size_t)rr * DI + kc * 128 + k];
            }
            __syncthreads();
            for (int k = 0; k < 128; ++k) {
                float a = As[lr][kc * 128 + k];
                acc[0] = fmaf(a, Ws[rg * 3 + 0][k], acc[0]);
                acc[1] = fmaf(a, Ws[rg * 3 + 1][k], acc[1]);
                acc[2] = fmaf(a, Ws[rg * 3 + 2][k], acc[2]);
            }
            __syncthreads();
        }
        dt_s[lr][rg * 3 + 0] = acc[0];
        dt_s[lr][rg * 3 + 1] = acc[1];
        dt_s[lr][rg * 3 + 2] = acc[2];
    }
    __syncthreads();
    // phase 3: scan-from-zero over the chunk
    {
        float Ar[16], Wd[16];
        for (int n = 0; n < 16; ++n) Ar[n] = -__expf(A_log[d * 16 + n]);
        for (int r = 0; r < 16; ++r) Wd[r] = W_dt[d * 16 + r];
        const float bd = b_dt[d];
        float q[16] = {};
        float Ssum = 0.f;
        for (int l = 0; l < 32; ++l) {
            float s = bd;
            for (int r = 0; r < 16; ++r) s = fmaf(dt_s[l][r], Wd[r], s);
            const float del = softplus_f(s);
            const float u = As[l][d];
            const float du = del * u;
            Ssum += del;
            for (int n = 0; n < 16; ++n) {
                float dA = __expf(del * Ar[n]);
                q[n] = fmaf(dA, q[n], du * dt_s[l][16 + n]);
            }
        }
        float* qo = Qb + ((size_t)blk * DI + d) * 16;
        for (int n = 0; n < 16; ++n) qo[n] = q[n];
        Sb[blk * DI + d] = Ssum;
    }
    if (c == 7 && d < 48) dtBC255[b * 48 + d] = dt_s[31][d];
}

// ---------------------------------------------------------------------------
// kC: compose chunks -> h(255), z(255) inline, gate -> gbuf, store h_state.
// ---------------------------------------------------------------------------
__global__ __launch_bounds__(512) void k_prefill_c(const float* __restrict__ x,
                                                   const float* __restrict__ W_in,
                                                   const float* __restrict__ Qb,
                                                   const float* __restrict__ Sb,
                                                   const float* __restrict__ dtBC255,
                                                   const float* __restrict__ xi_pre,
                                                   const float* __restrict__ conv_w,
                                                   const float* __restrict__ conv_b,
                                                   const float* __restrict__ A_log,
                                                   const float* __restrict__ Dp,
                                                   float* __restrict__ h_state,
                                                   float* __restrict__ gbuf) {
    __shared__ __align__(16) float xcol[256];
    const int b = blockIdx.x;
    const int d = threadIdx.x;
    if (d < 256) xcol[d] = x[(size_t)b * DM * LSEQ + d * LSEQ + 255];
    __syncthreads();
    float z = 0.f;
    {
        const float4* wr = (const float4*)&W_in[(size_t)(DI + d) * DM];
        const float4* xc4 = (const float4*)xcol;
        for (int k = 0; k < 64; ++k) {
            float4 w = wr[k], xx = xc4[k];
            z += w.x * xx.x + w.y * xx.y + w.z * xx.z + w.w * xx.w;
        }
    }
    float Ar[16];
    for (int n = 0; n < 16; ++n) Ar[n] = -__expf(A_log[d * 16 + n]);
    float h[16] = {};
    for (int c = 0; c < 8; ++c) {
        const int blk = b * 8 + c;
        const float S = Sb[blk * DI + d];
        const float* qv = Qb + ((size_t)blk * DI + d) * 16;
        for (int n = 0; n < 16; ++n) {
            float P = __expf(S * Ar[n]);
            h[n] = fmaf(P, h[n], qv[n]);
        }
    }
    float y = 0.f;
    for (int n = 0; n < 16; ++n) y = fmaf(h[n], dtBC255[b * 48 + 32 + n], y);
    float u;
    {
        float s = conv_b[d];
        for (int k = 0; k < 4; ++k)
            s = fmaf(conv_w[d * 4 + k], xi_pre[(size_t)(b * 256 + 252 + k) * DI + d], s);
        u = silu_f(s);
    }
    y = fmaf(u, Dp[d], y);
    gbuf[b * DI + d] = y * silu_f(z);
    float* ho = h_state + ((size_t)(b * DI + d)) * 16;
    for (int n = 0; n < 16; ++n) ho[n] = h[n];
}

// ---------------------------------------------------------------------------
// kD: persistent generation. 256 blocks = 16 batches x 16 slices, 512 thr.
// Wc slice in REGISTERS (64/thread); exchange = 64 floats/block + packed
// flag line; dtBC recomputed locally from full xin (W_x in LDS).
// ---------------------------------------------------------------------------
__global__ __launch_bounds__(512) void k_gen(
    const float* __restrict__ WcT, const float* __restrict__ W_out,
    const float* __restrict__ W_x, const float* __restrict__ W_dt,
    const float* __restrict__ conv_w, const float* __restrict__ conv_b,
    const float* __restrict__ b_dt, const float* __restrict__ A_log,
    const float* __restrict__ Dp, const float* __restrict__ xi_pre,
    const float* __restrict__ h_state, const float* __restrict__ gbuf0,
    float* __restrict__ xbuf, unsigned* __restrict__ flags,
    float* __restrict__ out) {
    const int bid = blockIdx.x;
    const int b = bid & 15;     // all 16 blocks of batch b share bid%8 -> one XCD
    const int p = bid >> 4;
    const int tid = threadIdx.x;

    __shared__ float wx_s[48][516];
    __shared__ float gs_s[512];
    __shared__ float xin_s[512];
    __shared__ float zs_s[512];
    __shared__ float red8[8][65];
    __shared__ float dtbc_s[48];
    __shared__ float hist[3][32];

    // ---- Wc slice into registers (coalesced: 64 contiguous floats/row) ----
    const int r = tid & 63, w = tid >> 6;
    float wc[64];
    {
        const float* src = WcT + (size_t)(w * 64) * 1024 + p * 64 + r;
        #pragma unroll
        for (int kk = 0; kk < 64; ++kk) wc[kk] = src[(size_t)kk * 1024];
    }
    // ---- W_x full into LDS ----
    for (int it = 0; it < 48; ++it) {
        int flat = it * 512 + tid;
        wx_s[flat >> 9][flat & 511] = W_x[flat];
    }
    // W_out row-slice in registers
    const int orow = p * 16 + (tid >> 5), osub = tid & 31;
    float wout[16];
    #pragma unroll
    for (int j = 0; j < 16; ++j) wout[j] = W_out[(size_t)orow * DI + osub + 32 * j];

    // per-thread scan state (d = tid)
    float wdt[16], Ar[16], h[16];
    {
        const float4* wp = (const float4*)&W_dt[tid * 16];
        const float4* ap = (const float4*)&A_log[tid * 16];
        const float4* hp = (const float4*)&h_state[((size_t)(b * DI + tid)) * 16];
        #pragma unroll
        for (int i = 0; i < 4; ++i) {
            float4 wv = wp[i], av = ap[i], hv = hp[i];
            wdt[4*i+0]=wv.x; wdt[4*i+1]=wv.y; wdt[4*i+2]=wv.z; wdt[4*i+3]=wv.w;
            Ar[4*i+0]=-__expf(av.x); Ar[4*i+1]=-__expf(av.y);
            Ar[4*i+2]=-__expf(av.z); Ar[4*i+3]=-__expf(av.w);
            h[4*i+0]=hv.x; h[4*i+1]=hv.y; h[4*i+2]=hv.z; h[4*i+3]=hv.w;
        }
    }
    const float bd = b_dt[tid];
    const float Dpv = Dp[tid];
    float cw0 = 0, cw1 = 0, cw2 = 0, cw3 = 0, cb = 0;
    if (tid < 32) {
        const int d = p * 32 + tid;
        cw0 = conv_w[d * 4 + 0]; cw1 = conv_w[d * 4 + 1];
        cw2 = conv_w[d * 4 + 2]; cw3 = conv_w[d * 4 + 3];
        cb  = conv_b[d];
        for (int k = 0; k < 3; ++k)
            hist[k][tid] = xi_pre[(size_t)(b * 256 + 253 + k) * DI + d];
    }
    gs_s[tid] = gbuf0[b * DI + tid];
    __syncthreads();

    for (int t = 0; t < TLEN; ++t) {
        if (t < TLEN - 1) {
            // preconv GEMV: row r (x-part r<32, z-part r>=32), K-slice w*64
            {
                const float4* g4 = (const float4*)&gs_s[w * 64];
                float s = 0.f;
                #pragma unroll
                for (int kk = 0; kk < 16; ++kk) {
                    float4 g = g4[kk];
                    s = fmaf(wc[4*kk+0], g.x, s);
                    s = fmaf(wc[4*kk+1], g.y, s);
                    s = fmaf(wc[4*kk+2], g.z, s);
                    s = fmaf(wc[4*kk+3], g.w, s);
                }
                red8[w][r] = s;
            }
            __syncthreads();
            if (tid < 64) {
                float v = 0.f;
                #pragma unroll
                for (int ss = 0; ss < 8; ++ss) v += red8[ss][tid];
                float outv;
                if (tid < 32) {
                    float xc = cb;
                    xc = fmaf(cw0, hist[t % 3][tid], xc);
                    xc = fmaf(cw1, hist[(t + 1) % 3][tid], xc);
                    xc = fmaf(cw2, hist[(t + 2) % 3][tid], xc);
                    xc = fmaf(cw3, v, xc);
                    hist[t % 3][tid] = v;
                    outv = silu_f(xc);
                } else {
                    outv = v;   // raw z
                }
                __hip_atomic_store(&xbuf[((size_t)((b * 16 + p) * 2 + (t & 1))) * 64 + tid],
                                   outv, __ATOMIC_RELAXED, __HIP_MEMORY_SCOPE_AGENT);
            }
            __syncthreads();   // drains stores (vmcnt 0 before barrier)
            if (tid == 0)
                __hip_atomic_store(&flags[b * 16 + p], (unsigned)(t + 1),
                                   __ATOMIC_RELEASE, __HIP_MEMORY_SCOPE_AGENT);
        }
        // output token t (overlaps other blocks' posting)
        {
            float s = 0.f;
            #pragma unroll
            for (int j = 0; j < 16; ++j) s = fmaf(wout[j], gs_s[osub + 32 * j], s);
            s += __shfl_down(s, 16); s += __shfl_down(s, 8);
            s += __shfl_down(s, 4);  s += __shfl_down(s, 2); s += __shfl_down(s, 1);
            if (osub == 0) out[(size_t)(b * 256 + orow) * TLEN + t] = s;
        }
        if (t == TLEN - 1) return;

        // poll packed flag line (one 64B line per batch)
        if (tid < 16) {
            while (__hip_atomic_load(&flags[b * 16 + tid],
                                     __ATOMIC_ACQUIRE, __HIP_MEMORY_SCOPE_AGENT)
                   < (unsigned)(t + 1))
                __builtin_amdgcn_s_sleep(1);
        }
        __syncthreads();
        // gather 16 x 64 floats
        #pragma unroll
        for (int i = 0; i < 2; ++i) {
            int idx = i * 512 + tid;
            int q = idx >> 6, pos = idx & 63;
            float v = __hip_atomic_load(
                xbuf + ((size_t)((b * 16 + q) * 2 + (t & 1))) * 64 + pos,
                __ATOMIC_RELAXED, __HIP_MEMORY_SCOPE_AGENT);
            if (pos < 32) xin_s[q * 32 + pos] = v;
            else          zs_s[q * 32 + pos - 32] = v;
        }
        __syncthreads();
        // full dtBC locally: 48 rows x K=512
        if (tid < 384) {
            const int rr = tid >> 3, sub = tid & 7;
            const float* wr = &wx_s[rr][sub * 64];
            const float* xv = &xin_s[sub * 64];
            float s = 0.f;
            #pragma unroll
            for (int k = 0; k < 64; ++k) s = fmaf(wr[k], xv[k], s);
            s += __shfl_down(s, 4); s += __shfl_down(s, 2); s += __shfl_down(s, 1);
            if (sub == 0) dtbc_s[rr] = s;
        }
        __syncthreads();
        // replicated scan step (d = tid)
        {
            float dt_l = bd;
            #pragma unroll
            for (int rr = 0; rr < 16; ++rr) dt_l = fmaf(dtbc_s[rr], wdt[rr], dt_l);
            const float del = softplus_f(dt_l);
            const float u = xin_s[tid];
            const float du = del * u;
            float y = 0.f;
            #pragma unroll
            for (int n = 0; n < 16; ++n) {
                float dA = __expf(del * Ar[n]);
                h[n] = fmaf(dA, h[n], du * dtbc_s[16 + n]);
                y = fmaf(h[n], dtbc_s[32 + n], y);
            }
            y = fmaf(u, Dpv, y);
            gs_s[tid] = y * silu_f(zs_s[tid]);
        }
        __syncthreads();
    }
}

// ---------------------------------------------------------------------------
extern "C" void kernel_launch(void* const* d_in, const int* in_sizes, int n_in,
                              void* d_out, int out_size, void* d_ws, size_t ws_size,
                              hipStream_t stream) {
    const float* x      = (const float*)d_in[0];
    const float* W_in   = (const float*)d_in[1];
    const float* conv_w = (const float*)d_in[2];
    const float* conv_b = (const float*)d_in[3];
    const float* W_x    = (const float*)d_in[4];
    const float* W_dt   = (const float*)d_in[5];
    const float* b_dt   = (const float*)d_in[6];
    const float* A_log  = (const float*)d_in[7];
    const float* Dp     = (const float*)d_in[8];
    const float* W_out  = (const float*)d_in[9];
    float* out = (float*)d_out;

    float* base = (float*)d_ws;
    size_t off = 0;
    auto alloc = [&](size_t n) { float* pp = base + off; off += (n + 15) & ~(size_t)15; return pp; };
    unsigned* flags = (unsigned*)alloc(256);
    float* xbuf     = alloc((size_t)16 * 16 * 2 * 64);
    float* gbuf     = alloc(16 * 512);
    float* h_state  = alloc((size_t)16 * 512 * 16);
    float* dtBC255  = alloc(16 * 48);
    float* Sb       = alloc((size_t)128 * 512);
    float* Qb       = alloc((size_t)128 * 512 * 16);
    float* xi_pre   = alloc((size_t)4096 * 512);
    float* WcT      = alloc((size_t)512 * 1024);

    hipMemsetAsync(flags, 0, 256 * sizeof(unsigned), stream);
    hipLaunchKernelGGL(k_prefill_a, dim3(640), dim3(256), 0, stream,
                       x, W_in, W_out, WcT, xi_pre);
    hipLaunchKernelGGL(k_prefill_b, dim3(128), dim3(512), 0, stream,
                       xi_pre, conv_w, conv_b, W_x, W_dt, b_dt, A_log, Qb, Sb, dtBC255);
    hipLaunchKernelGGL(k_prefill_c, dim3(16), dim3(512), 0, stream,
                       x, W_in, Qb, Sb, dtBC255, xi_pre, conv_w, conv_b, A_log, Dp,
                       h_state, gbuf);
    hipLaunchKernelGGL(k_gen, dim3(256), dim3(512), 0, stream,
                       WcT, W_out, W_x, W_dt, conv_w, conv_b, b_dt, A_log, Dp,
                       xi_pre, h_state, gbuf, xbuf, flags, out);
}

// Round 6
// 339.703 us; speedup vs baseline: 1.2499x; 1.0519x over previous
//
#include <hip/hip_runtime.h>
#include <cmath>

#define DEV __device__ __forceinline__

constexpr int B_SZ = 16;
constexpr int LSEQ = 256;
constexpr int DM   = 256;   // d_model
constexpr int DI   = 512;   // d_inner
constexpr int TLEN = 16;

DEV float silu_f(float x)     { return x / (1.f + __expf(-x)); }
DEV float softplus_f(float x) { return log1pf(__expf(x)); }

// ---------------------------------------------------------------------------
// kA: blocks [0,128): fold WcT[k][newc] = (W_in·W_out)^T in gen-sliced layout
//     blocks [128,640): in-projection xi_pre = x^T @ W_in(x-part)^T
// ---------------------------------------------------------------------------
__global__ __launch_bounds__(256) void k_prefill_a(const float* __restrict__ x,
                                                   const float* __restrict__ W_in,
                                                   const float* __restrict__ W_out,
                                                   float* __restrict__ WcT,
                                                   float* __restrict__ xi_pre) {
    __shared__ float smem[2][32][68];
    const int tid = threadIdx.x;
    const int ty = tid >> 4, tx = tid & 15;
    float acc[4][4] = {};
    if (blockIdx.x < 128) {
        // ---- fold: tile j0 (Wc row) x d0 (Wc col) ----
        const int j0 = (int)(blockIdx.x & 15) * 64;
        const int d0 = (int)(blockIdx.x >> 4) * 64;
        float (*As)[68] = smem[0];
        float (*Bs)[68] = smem[1];
        for (int kc = 0; kc < DM; kc += 32) {
            for (int it = 0; it < 8; ++it) {
                int idx = it * 256 + tid;
                int jj = idx >> 5, kk = idx & 31;
                As[kk][jj] = W_in[(size_t)(j0 + jj) * DM + kc + kk];
            }
            for (int it = 0; it < 8; ++it) {
                int idx = it * 256 + tid;
                int kk = idx >> 6, dd = idx & 63;
                Bs[kk][dd] = W_out[(size_t)(kc + kk) * DI + d0 + dd];
            }
            __syncthreads();
            for (int kk = 0; kk < 32; ++kk) {
                float4 a4 = *(const float4*)&As[kk][ty * 4];
                float4 b4 = *(const float4*)&Bs[kk][tx * 4];
                float av[4] = {a4.x, a4.y, a4.z, a4.w};
                float bv[4] = {b4.x, b4.y, b4.z, b4.w};
                for (int i = 0; i < 4; ++i)
                    for (int j = 0; j < 4; ++j) acc[i][j] = fmaf(av[i], bv[j], acc[i][j]);
            }
            __syncthreads();
        }
        // transpose via LDS, then store rows=k(d), cols=gen-sliced j
        float (*Cs)[65] = (float(*)[65])&smem[0][0][0];
        for (int i = 0; i < 4; ++i)
            for (int j = 0; j < 4; ++j)
                Cs[ty * 4 + i][tx * 4 + j] = acc[i][j];
        __syncthreads();
        const int dr = tid >> 2, jq = tid & 3;
        for (int ii = 0; ii < 4; ++ii) {
            int jl = jq * 16 + ii * 4;
            int jg = j0 + jl;
            int newc;
            if (jg < DI) newc = (jg >> 5) * 64 + (jg & 31);
            else { int jz = jg - DI; newc = (jz >> 5) * 64 + 32 + (jz & 31); }
            float4 v = make_float4(Cs[jl][dr], Cs[jl + 1][dr], Cs[jl + 2][dr], Cs[jl + 3][dr]);
            *(float4*)&WcT[(size_t)(d0 + dr) * 1024 + newc] = v;
        }
    } else {
        // ---- inproj tile ----
        const int bid2 = (int)blockIdx.x - 128;
        const int bx = bid2 & 7, by = bid2 >> 3;
        const int row0 = by * 64;
        const int b = row0 >> 8, l0 = row0 & 255;
        const int j0 = bx * 64;
        float (*As)[68] = smem[0];
        float (*Ws)[68] = smem[1];
        const float* xb = x + (size_t)b * DM * LSEQ;
        for (int kc = 0; kc < DM; kc += 32) {
            for (int it = 0; it < 8; ++it) {
                int idx = it * 256 + tid;
                int kk = idx >> 6, li = idx & 63;
                As[kk][li] = xb[(kc + kk) * LSEQ + l0 + li];
            }
            for (int it = 0; it < 8; ++it) {
                int idx = it * 256 + tid;
                int jj = idx >> 5, kk = idx & 31;
                Ws[kk][jj] = W_in[(size_t)(j0 + jj) * DM + kc + kk];
            }
            __syncthreads();
            for (int kk = 0; kk < 32; ++kk) {
                float4 a4 = *(const float4*)&As[kk][ty * 4];
                float4 w4 = *(const float4*)&Ws[kk][tx * 4];
                float av[4] = {a4.x, a4.y, a4.z, a4.w};
                float wv[4] = {w4.x, w4.y, w4.z, w4.w};
                for (int i = 0; i < 4; ++i)
                    for (int j = 0; j < 4; ++j) acc[i][j] = fmaf(av[i], wv[j], acc[i][j]);
            }
            __syncthreads();
        }
        for (int i = 0; i < 4; ++i) {
            float4 v = make_float4(acc[i][0], acc[i][1], acc[i][2], acc[i][3]);
            *(float4*)&xi_pre[(size_t)(row0 + ty * 4 + i) * DI + j0 + tx * 4] = v;
        }
    }
}

// ---------------------------------------------------------------------------
// kB: fused conv+silu -> dtBC GEMM -> chunked scan, per (b, chunk).
// 128 blocks x 512 threads. Emits Qb/Sb; chunk 7 also emits dtBC row 255.
// ---------------------------------------------------------------------------
__global__ __launch_bounds__(512) void k_prefill_b(const float* __restrict__ xi_pre,
                                                   const float* __restrict__ conv_w,
                                                   const float* __restrict__ conv_b,
                                                   const float* __restrict__ W_x,
                                                   const float* __restrict__ W_dt,
                                                   const float* __restrict__ b_dt,
                                                   const float* __restrict__ A_log,
                                                   float* __restrict__ Qb,
                                                   float* __restrict__ Sb,
                                                   float* __restrict__ dtBC255) {
    __shared__ float As[32][516];
    __shared__ float Ws[48][129];
    __shared__ float dt_s[32][49];
    const int blk = blockIdx.x;
    const int b = blk >> 3, c = blk & 7;
    const int d = threadIdx.x;
    const int l0 = c * 32;
    // phase 1: conv + silu into As
    {
        const float c0 = conv_w[d * 4 + 0], c1 = conv_w[d * 4 + 1];
        const float c2 = conv_w[d * 4 + 2], c3 = conv_w[d * 4 + 3];
        const float cbv = conv_b[d];
        float p0, p1, p2;
        int l;
        l = l0 - 3; p0 = (l >= 0) ? xi_pre[(size_t)(b * 256 + l) * DI + d] : 0.f;
        l = l0 - 2; p1 = (l >= 0) ? xi_pre[(size_t)(b * 256 + l) * DI + d] : 0.f;
        l = l0 - 1; p2 = (l >= 0) ? xi_pre[(size_t)(b * 256 + l) * DI + d] : 0.f;
        for (int ll = 0; ll < 32; ++ll) {
            float v = xi_pre[(size_t)(b * 256 + l0 + ll) * DI + d];
            As[ll][d] = silu_f(cbv + c0 * p0 + c1 * p1 + c2 * p2 + c3 * v);
            p0 = p1; p1 = p2; p2 = v;
        }
    }
    __syncthreads();
    // phase 2: dt_s[l][r] = sum_d As[l][d] * W_x[r][d]
    {
        const int lr = d >> 4, rg = d & 15;
        float acc[3] = {};
        for (int kc = 0; kc < 4; ++kc) {
            for (int it = 0; it < 12; ++it) {
                int idx = it * 512 + d;
                int rr = idx >> 7, k = idx & 127;
                Ws[rr][k] = W_x[(size_t)rr * DI + kc * 128 + k];
            }
            __syncthreads();
            for (int k = 0; k < 128; ++k) {
                float a = As[lr][kc * 128 + k];
                acc[0] = fmaf(a, Ws[rg * 3 + 0][k], acc[0]);
                acc[1] = fmaf(a, Ws[rg * 3 + 1][k], acc[1]);
                acc[2] = fmaf(a, Ws[rg * 3 + 2][k], acc[2]);
            }
            __syncthreads();
        }
        dt_s[lr][rg * 3 + 0] = acc[0];
        dt_s[lr][rg * 3 + 1] = acc[1];
        dt_s[lr][rg * 3 + 2] = acc[2];
    }
    __syncthreads();
    // phase 3: scan-from-zero over the chunk
    {
        float Ar[16], Wd[16];
        for (int n = 0; n < 16; ++n) Ar[n] = -__expf(A_log[d * 16 + n]);
        for (int r = 0; r < 16; ++r) Wd[r] = W_dt[d * 16 + r];
        const float bd = b_dt[d];
        float q[16] = {};
        float Ssum = 0.f;
        for (int l = 0; l < 32; ++l) {
            float s = bd;
            for (int r = 0; r < 16; ++r) s = fmaf(dt_s[l][r], Wd[r], s);
            const float del = softplus_f(s);
            const float u = As[l][d];
            const float du = del * u;
            Ssum += del;
            for (int n = 0; n < 16; ++n) {
                float dA = __expf(del * Ar[n]);
                q[n] = fmaf(dA, q[n], du * dt_s[l][16 + n]);
            }
        }
        float* qo = Qb + ((size_t)blk * DI + d) * 16;
        for (int n = 0; n < 16; ++n) qo[n] = q[n];
        Sb[blk * DI + d] = Ssum;
    }
    if (c == 7 && d < 48) dtBC255[b * 48 + d] = dt_s[31][d];
}

// ---------------------------------------------------------------------------
// kC: compose chunks -> h(255), z(255) inline, gate -> gbuf, store h_state.
// ---------------------------------------------------------------------------
__global__ __launch_bounds__(512) void k_prefill_c(const float* __restrict__ x,
                                                   const float* __restrict__ W_in,
                                                   const float* __restrict__ Qb,
                                                   const float* __restrict__ Sb,
                                                   const float* __restrict__ dtBC255,
                                                   const float* __restrict__ xi_pre,
                                                   const float* __restrict__ conv_w,
                                                   const float* __restrict__ conv_b,
                                                   const float* __restrict__ A_log,
                                                   const float* __restrict__ Dp,
                                                   float* __restrict__ h_state,
                                                   float* __restrict__ gbuf) {
    __shared__ __align__(16) float xcol[256];
    const int b = blockIdx.x;
    const int d = threadIdx.x;
    if (d < 256) xcol[d] = x[(size_t)b * DM * LSEQ + d * LSEQ + 255];
    __syncthreads();
    float z = 0.f;
    {
        const float4* wr = (const float4*)&W_in[(size_t)(DI + d) * DM];
        const float4* xc4 = (const float4*)xcol;
        for (int k = 0; k < 64; ++k) {
            float4 w = wr[k], xx = xc4[k];
            z += w.x * xx.x + w.y * xx.y + w.z * xx.z + w.w * xx.w;
        }
    }
    float Ar[16];
    for (int n = 0; n < 16; ++n) Ar[n] = -__expf(A_log[d * 16 + n]);
    float h[16] = {};
    for (int c = 0; c < 8; ++c) {
        const int blk = b * 8 + c;
        const float S = Sb[blk * DI + d];
        const float* qv = Qb + ((size_t)blk * DI + d) * 16;
        for (int n = 0; n < 16; ++n) {
            float P = __expf(S * Ar[n]);
            h[n] = fmaf(P, h[n], qv[n]);
        }
    }
    float y = 0.f;
    for (int n = 0; n < 16; ++n) y = fmaf(h[n], dtBC255[b * 48 + 32 + n], y);
    float u;
    {
        float s = conv_b[d];
        for (int k = 0; k < 4; ++k)
            s = fmaf(conv_w[d * 4 + k], xi_pre[(size_t)(b * 256 + 252 + k) * DI + d], s);
        u = silu_f(s);
    }
    y = fmaf(u, Dp[d], y);
    gbuf[b * DI + d] = y * silu_f(z);
    float* ho = h_state + ((size_t)(b * DI + d)) * 16;
    for (int n = 0; n < 16; ++n) ho[n] = h[n];
}

// ---------------------------------------------------------------------------
// kD: persistent generation. 256 blocks = 16 batches x 16 slices, 512 thr.
// Wc slice PINNED in registers (asm barrier prevents load sinking);
// exchange = 64 floats/block + packed flag line; dtBC recomputed locally
// (odd-stride W_x LDS -> conflict-free).
// ---------------------------------------------------------------------------
__global__ __launch_bounds__(512, 2) void k_gen(
    const float* __restrict__ WcT, const float* __restrict__ W_out,
    const float* __restrict__ W_x, const float* __restrict__ W_dt,
    const float* __restrict__ conv_w, const float* __restrict__ conv_b,
    const float* __restrict__ b_dt, const float* __restrict__ A_log,
    const float* __restrict__ Dp, const float* __restrict__ xi_pre,
    const float* __restrict__ h_state, const float* __restrict__ gbuf0,
    float* __restrict__ xbuf, unsigned* __restrict__ flags,
    float* __restrict__ out) {
    const int bid = blockIdx.x;
    const int b = bid & 15;     // all 16 blocks of batch b share bid%8 -> one XCD
    const int p = bid >> 4;
    const int tid = threadIdx.x;

    __shared__ float wx_s[48][517];   // ODD stride: conflict-free row-major reads
    __shared__ float gs_s[512];
    __shared__ float xin_s[512];
    __shared__ float zs_s[512];
    __shared__ float red8[8][65];
    __shared__ float dtbc_s[48];
    __shared__ float hist[3][32];

    // ---- Wc slice into registers (coalesced: 64 contiguous floats/row) ----
    const int r = tid & 63, w = tid >> 6;
    float wc[64];
    {
        const float* src = WcT + (size_t)(w * 64) * 1024 + p * 64 + r;
        #pragma unroll
        for (int kk = 0; kk < 64; ++kk) wc[kk] = src[(size_t)kk * 1024];
    }
    // PIN: opaque asm makes these VGPR-canonical — compiler cannot re-load
    #pragma unroll
    for (int kk = 0; kk < 64; ++kk) asm volatile("" : "+v"(wc[kk]));

    // ---- W_x full into LDS (odd stride 517) ----
    for (int it = 0; it < 48; ++it) {
        int flat = it * 512 + tid;
        wx_s[flat >> 9][flat & 511] = W_x[flat];
    }
    // W_out row-slice in registers
    const int orow = p * 16 + (tid >> 5), osub = tid & 31;
    float wout[16];
    #pragma unroll
    for (int j = 0; j < 16; ++j) wout[j] = W_out[(size_t)orow * DI + osub + 32 * j];
    #pragma unroll
    for (int j = 0; j < 16; ++j) asm volatile("" : "+v"(wout[j]));

    // per-thread scan state (d = tid)
    float wdt[16], Ar[16], h[16];
    {
        const float4* wp = (const float4*)&W_dt[tid * 16];
        const float4* ap = (const float4*)&A_log[tid * 16];
        const float4* hp = (const float4*)&h_state[((size_t)(b * DI + tid)) * 16];
        #pragma unroll
        for (int i = 0; i < 4; ++i) {
            float4 wv = wp[i], av = ap[i], hv = hp[i];
            wdt[4*i+0]=wv.x; wdt[4*i+1]=wv.y; wdt[4*i+2]=wv.z; wdt[4*i+3]=wv.w;
            Ar[4*i+0]=-__expf(av.x); Ar[4*i+1]=-__expf(av.y);
            Ar[4*i+2]=-__expf(av.z); Ar[4*i+3]=-__expf(av.w);
            h[4*i+0]=hv.x; h[4*i+1]=hv.y; h[4*i+2]=hv.z; h[4*i+3]=hv.w;
        }
    }
    #pragma unroll
    for (int i = 0; i < 16; ++i) asm volatile("" : "+v"(wdt[i]));
    const float bd = b_dt[tid];
    const float Dpv = Dp[tid];
    float cw0 = 0, cw1 = 0, cw2 = 0, cw3 = 0, cb = 0;
    if (tid < 32) {
        const int d = p * 32 + tid;
        cw0 = conv_w[d * 4 + 0]; cw1 = conv_w[d * 4 + 1];
        cw2 = conv_w[d * 4 + 2]; cw3 = conv_w[d * 4 + 3];
        cb  = conv_b[d];
        for (int k = 0; k < 3; ++k)
            hist[k][tid] = xi_pre[(size_t)(b * 256 + 253 + k) * DI + d];
    }
    gs_s[tid] = gbuf0[b * DI + tid];
    __syncthreads();

    for (int t = 0; t < TLEN; ++t) {
        if (t < TLEN - 1) {
            // preconv GEMV: row r (x-part r<32, z-part r>=32), K-slice w*64
            {
                const float4* g4 = (const float4*)&gs_s[w * 64];
                float s = 0.f;
                #pragma unroll
                for (int kk = 0; kk < 16; ++kk) {
                    float4 g = g4[kk];
                    s = fmaf(wc[4*kk+0], g.x, s);
                    s = fmaf(wc[4*kk+1], g.y, s);
                    s = fmaf(wc[4*kk+2], g.z, s);
                    s = fmaf(wc[4*kk+3], g.w, s);
                }
                red8[w][r] = s;
            }
            __syncthreads();
            if (tid < 64) {
                float v = 0.f;
                #pragma unroll
                for (int ss = 0; ss < 8; ++ss) v += red8[ss][tid];
                float outv;
                if (tid < 32) {
                    float xc = cb;
                    xc = fmaf(cw0, hist[t % 3][tid], xc);
                    xc = fmaf(cw1, hist[(t + 1) % 3][tid], xc);
                    xc = fmaf(cw2, hist[(t + 2) % 3][tid], xc);
                    xc = fmaf(cw3, v, xc);
                    hist[t % 3][tid] = v;
                    outv = silu_f(xc);
                } else {
                    outv = v;   // raw z
                }
                __hip_atomic_store(&xbuf[((size_t)((b * 16 + p) * 2 + (t & 1))) * 64 + tid],
                                   outv, __ATOMIC_RELAXED, __HIP_MEMORY_SCOPE_AGENT);
            }
            __syncthreads();   // drains stores (vmcnt 0 before barrier)
            if (tid == 0)
                __hip_atomic_store(&flags[b * 16 + p], (unsigned)(t + 1),
                                   __ATOMIC_RELEASE, __HIP_MEMORY_SCOPE_AGENT);
        }
        // output token t (overlaps other blocks' posting)
        {
            float s = 0.f;
            #pragma unroll
            for (int j = 0; j < 16; ++j) s = fmaf(wout[j], gs_s[osub + 32 * j], s);
            s += __shfl_down(s, 16); s += __shfl_down(s, 8);
            s += __shfl_down(s, 4);  s += __shfl_down(s, 2); s += __shfl_down(s, 1);
            if (osub == 0) out[(size_t)(b * 256 + orow) * TLEN + t] = s;
        }
        if (t == TLEN - 1) return;

        // poll packed flag line (one 64B line per batch)
        if (tid < 16) {
            while (__hip_atomic_load(&flags[b * 16 + tid],
                                     __ATOMIC_ACQUIRE, __HIP_MEMORY_SCOPE_AGENT)
                   < (unsigned)(t + 1))
                __builtin_amdgcn_s_sleep(1);
        }
        __syncthreads();
        // gather 16 x 64 floats
        #pragma unroll
        for (int i = 0; i < 2; ++i) {
            int idx = i * 512 + tid;
            int q = idx >> 6, pos = idx & 63;
            float v = __hip_atomic_load(
                xbuf + ((size_t)((b * 16 + q) * 2 + (t & 1))) * 64 + pos,
                __ATOMIC_RELAXED, __HIP_MEMORY_SCOPE_AGENT);
            if (pos < 32) xin_s[q * 32 + pos] = v;
            else          zs_s[q * 32 + pos - 32] = v;
        }
        __syncthreads();
        // full dtBC locally: lane = row (conflict-free via odd stride), wave = K-slice
        {
            const int rr = tid & 63, ks = tid >> 6;
            float s = 0.f;
            if (rr < 48) {
                const float* wr = &wx_s[rr][ks * 64];
                const float* xv = &xin_s[ks * 64];
                #pragma unroll
                for (int k = 0; k < 64; ++k) s = fmaf(wr[k], xv[k], s);
            }
            red8[ks][rr] = s;
        }
        __syncthreads();
        if (tid < 48) {
            float s = 0.f;
            #pragma unroll
            for (int ss = 0; ss < 8; ++ss) s += red8[ss][tid];
            dtbc_s[tid] = s;
        }
        __syncthreads();
        // replicated scan step (d = tid)
        {
            float dt_l = bd;
            #pragma unroll
            for (int rr = 0; rr < 16; ++rr) dt_l = fmaf(dtbc_s[rr], wdt[rr], dt_l);
            const float del = softplus_f(dt_l);
            const float u = xin_s[tid];
            const float du = del * u;
            float y = 0.f;
            #pragma unroll
            for (int n = 0; n < 16; ++n) {
                float dA = __expf(del * Ar[n]);
                h[n] = fmaf(dA, h[n], du * dtbc_s[16 + n]);
                y = fmaf(h[n], dtbc_s[32 + n], y);
            }
            y = fmaf(u, Dpv, y);
            gs_s[tid] = y * silu_f(zs_s[tid]);
        }
        __syncthreads();
    }
}

// ---------------------------------------------------------------------------
extern "C" void kernel_launch(void* const* d_in, const int* in_sizes, int n_in,
                              void* d_out, int out_size, void* d_ws, size_t ws_size,
                              hipStream_t stream) {
    const float* x      = (const float*)d_in[0];
    const float* W_in   = (const float*)d_in[1];
    const float* conv_w = (const float*)d_in[2];
    const float* conv_b = (const float*)d_in[3];
    const float* W_x    = (const float*)d_in[4];
    const float* W_dt   = (const float*)d_in[5];
    const float* b_dt   = (const float*)d_in[6];
    const float* A_log  = (const float*)d_in[7];
    const float* Dp     = (const float*)d_in[8];
    const float* W_out  = (const float*)d_in[9];
    float* out = (float*)d_out;

    float* base = (float*)d_ws;
    size_t off = 0;
    auto alloc = [&](size_t n) { float* pp = base + off; off += (n + 15) & ~(size_t)15; return pp; };
    unsigned* flags = (unsigned*)alloc(256);
    float* xbuf     = alloc((size_t)16 * 16 * 2 * 64);
    float* gbuf     = alloc(16 * 512);
    float* h_state  = alloc((size_t)16 * 512 * 16);
    float* dtBC255  = alloc(16 * 48);
    float* Sb       = alloc((size_t)128 * 512);
    float* Qb       = alloc((size_t)128 * 512 * 16);
    float* xi_pre   = alloc((size_t)4096 * 512);
    float* WcT      = alloc((size_t)512 * 1024);

    hipMemsetAsync(flags, 0, 256 * sizeof(unsigned), stream);
    hipLaunchKernelGGL(k_prefill_a, dim3(640), dim3(256), 0, stream,
                       x, W_in, W_out, WcT, xi_pre);
    hipLaunchKernelGGL(k_prefill_b, dim3(128), dim3(512), 0, stream,
                       xi_pre, conv_w, conv_b, W_x, W_dt, b_dt, A_log, Qb, Sb, dtBC255);
    hipLaunchKernelGGL(k_prefill_c, dim3(16), dim3(512), 0, stream,
                       x, W_in, Qb, Sb, dtBC255, xi_pre, conv_w, conv_b, A_log, Dp,
                       h_state, gbuf);
    hipLaunchKernelGGL(k_gen, dim3(256), dim3(512), 0, stream,
                       WcT, W_out, W_x, W_dt, conv_w, conv_b, b_dt, A_log, Dp,
                       xi_pre, h_state, gbuf, xbuf, flags, out);
}